// Round 17
// baseline (649.565 us; speedup 1.0000x reference)
//
#include <hip/hip_runtime.h>

#define BATCH  8
#define NPTS   16384
#define LVOX   605     // 11*11*5 = 121 xy-columns * 5 z
#define ABINS  8
#define CH     23
#define NCOL   121
#define NBIN   14      // floor(d) <= 13 (max dist 13.89); feature[14] == 1.0
#define BPTS   256     // points per feature block
#define FEAT_BLOCKS (BATCH * (NPTS / BPTS))   // 512
#define ROT_CH    4
#define ROT_CHPTS (NPTS / ROT_CH)             // 4096
#define ROT_BLOCKS (ABINS * BATCH * ROT_CH)   // 256

#define ROT_WS_U32  (ABINS * BATCH * LVOX)          // 38720
#define FEAT_WS_U32 (BATCH * LVOX * (NBIN / 2))     // 33880 (u16 pairs)
#define WS_U32_TOTAL (ROT_WS_U32 + FEAT_WS_U32)     // 72600

#define MASK8 0x0F0F0F0F0F0F0F0Full
#define REP   8

// ---------------------------------------------------------------------------
// Ablation probes (R17).  8x-repeated R14 feature loop variants, each long
// enough (>>39us) to surface in the rocprof top-5 with counters.
// V0 full | V1 no-atomic | V2 no-sqrt | V3 atomic-only | V4 register-nibble.
// Probes write only into ws (wiped by zero_kernel afterwards).
// ---------------------------------------------------------------------------
template<int V>
__global__ __launch_bounds__(512) void probe_kernel(const float* __restrict__ pcd,
                                                    unsigned* __restrict__ sink) {
    __shared__ unsigned hist[5][NBIN][128];
    const int bid = blockIdx.x;
    const int tid = threadIdx.x;
    { unsigned* hp = &hist[0][0][0];
      for (int i = tid; i < 5 * NBIN * 128; i += 512) hp[i] = 0u; }

    const int li = tid & 127;
    const int cc = (li < NCOL) ? li : (NCOL - 1);
    const float lx = -5.0f + (float)(cc / 11);
    const float ly = -5.0f + (float)(cc % 11);
    const int b = bid >> 6, outer = bid & 63;
    const int pbase = __builtin_amdgcn_readfirstlane(tid >> 7) * 64;
    const float* pp0 = pcd + ((size_t)b * NPTS + outer * BPTS + pbase) * 3;
    __syncthreads();

    unsigned long long acc_sink = 0;
#pragma unroll 1
    for (int rep = 0; rep < REP; ++rep) {
        unsigned long long ppb = (unsigned long long)pp0;
        asm volatile("" : "+s"(ppb));             // defeat cross-rep hoisting
        const float* __restrict__ pp = (const float*)ppb;

        if constexpr (V == 3) {
            // pure LDS-atomic stream, minimal VALU
#pragma unroll 4
            for (int j = 0; j < 64; ++j) {
                const int k = (j + li) & 7;
#pragma unroll
                for (int z = 0; z < 5; ++z) atomicAdd(&hist[z][k][li], 1u);
            }
        } else if constexpr (V == 4) {
            // register nibble accumulate (R5 path), zero LDS in loop
            unsigned long long be0=0,bo0=0,be1=0,bo1=0,be2=0,bo2=0,be3=0,bo3=0,be4=0,bo4=0;
#define PTN(J)                                                                  \
            {                                                                   \
                const float px = pp[(J)*3+0], py = pp[(J)*3+1], pz = pp[(J)*3+2];\
                const float dx = px - lx, dy = py - ly;                         \
                const float rxy2 = fmaf(dy, dy, dx * dx);                       \
                const float dz0 = pz + 2.0f;                                    \
                { const float dz=dz0;      n0 += 1ull << (((int)__builtin_amdgcn_sqrtf(fmaf(dz,dz,rxy2)))<<2); } \
                { const float dz=dz0-1.0f; n1 += 1ull << (((int)__builtin_amdgcn_sqrtf(fmaf(dz,dz,rxy2)))<<2); } \
                { const float dz=dz0-2.0f; n2 += 1ull << (((int)__builtin_amdgcn_sqrtf(fmaf(dz,dz,rxy2)))<<2); } \
                { const float dz=dz0-3.0f; n3 += 1ull << (((int)__builtin_amdgcn_sqrtf(fmaf(dz,dz,rxy2)))<<2); } \
                { const float dz=dz0-4.0f; n4 += 1ull << (((int)__builtin_amdgcn_sqrtf(fmaf(dz,dz,rxy2)))<<2); } \
            }
#pragma unroll 1
            for (int g = 0; g < 4; ++g) {
                unsigned long long n0=0,n1=0,n2=0,n3=0,n4=0;
#pragma unroll
                for (int jj = 0; jj < 15; ++jj) PTN(g * 15 + jj)
                be0+=n0&MASK8; bo0+=(n0>>4)&MASK8; be1+=n1&MASK8; bo1+=(n1>>4)&MASK8;
                be2+=n2&MASK8; bo2+=(n2>>4)&MASK8; be3+=n3&MASK8; bo3+=(n3>>4)&MASK8;
                be4+=n4&MASK8; bo4+=(n4>>4)&MASK8;
            }
            {
                unsigned long long n0=0,n1=0,n2=0,n3=0,n4=0;
#pragma unroll
                for (int j = 60; j < 64; ++j) PTN(j)
                be0+=n0&MASK8; bo0+=(n0>>4)&MASK8; be1+=n1&MASK8; bo1+=(n1>>4)&MASK8;
                be2+=n2&MASK8; bo2+=(n2>>4)&MASK8; be3+=n3&MASK8; bo3+=(n3>>4)&MASK8;
                be4+=n4&MASK8; bo4+=(n4>>4)&MASK8;
            }
#undef PTN
            acc_sink += be0+bo0+be1+bo1+be2+bo2+be3+bo3+be4+bo4;
        } else {
            // V0 / V1 / V2
#pragma unroll 4
            for (int j = 0; j < 64; ++j) {
                const float px = pp[j*3+0], py = pp[j*3+1], pz = pp[j*3+2];
                const float dx = px - lx, dy = py - ly;
                const float rxy2 = fmaf(dy, dy, dx * dx);
                const float dz0 = pz + 2.0f;
#pragma unroll
                for (int z = 0; z < 5; ++z) {
                    const float dz = dz0 - (float)z;
                    const float d2 = fmaf(dz, dz, rxy2);
                    int k;
                    if constexpr (V == 2) k = (int)(d2 * 0.07216f);  // <=13 for d2<=192.75
                    else k = (int)__builtin_amdgcn_sqrtf(d2);
                    if constexpr (V == 1) { asm volatile("" :: "v"(k)); }
                    else atomicAdd(&hist[z][k][li], 1u);
                }
            }
        }
    }
    const unsigned s = hist[0][tid % NBIN][li] + hist[4][(tid + 3) % NBIN][li]
                     + (unsigned)acc_sink;
    if (tid < 64) sink[bid * 64 + tid] = s;      // keep live; zeroed later
}

// ---------------------------------------------------------------------------
// Workspace zeroing — wipes probe garbage, then real accumulation starts.
// ---------------------------------------------------------------------------
__global__ __launch_bounds__(256) void zero_kernel(unsigned* __restrict__ ws) {
    const int i = blockIdx.x * 256 + threadIdx.x;
    if (i < WS_U32_TOTAL) ws[i] = 0u;
}

// ---------------------------------------------------------------------------
// Fused main kernel — R14 EXACT (best known: 35.6us total).
// ---------------------------------------------------------------------------
__global__ __launch_bounds__(512) void main_kernel(const float* __restrict__ pcd,
                                                   int* __restrict__ rot_hist,
                                                   unsigned* __restrict__ feat_hist) {
    __shared__ unsigned hist[5][NBIN][128];
    const int bid = blockIdx.x;
    const int tid = threadIdx.x;

    if (bid < FEAT_BLOCKS) {
        const int b     = bid >> 6;
        const int outer = bid & 63;
        { unsigned* hp = &hist[0][0][0];
          for (int i = tid; i < 5 * NBIN * 128; i += 512) hp[i] = 0u; }

        const int li = tid & 127;
        const int cc = (li < NCOL) ? li : (NCOL - 1);
        const float lx = -5.0f + (float)(cc / 11);
        const float ly = -5.0f + (float)(cc % 11);
        const int pbase = __builtin_amdgcn_readfirstlane(tid >> 7) * 64;
        const float* __restrict__ pp =
            pcd + ((size_t)b * NPTS + outer * BPTS + pbase) * 3;

        __syncthreads();

#pragma unroll 4
        for (int j = 0; j < 64; ++j) {
            const float px = pp[j * 3 + 0];
            const float py = pp[j * 3 + 1];
            const float pz = pp[j * 3 + 2];
            const float dx = px - lx, dy = py - ly;
            const float rxy2 = fmaf(dy, dy, dx * dx);
            const float dz0 = pz + 2.0f;
#pragma unroll
            for (int z = 0; z < 5; ++z) {
                const float dz = dz0 - (float)z;
                const float d  = __builtin_amdgcn_sqrtf(fmaf(dz, dz, rxy2));
                atomicAdd(&hist[z][(int)d][li], 1u);
            }
        }
        __syncthreads();

        for (int item = tid; item < NCOL * 5 * (NBIN / 2); item += 512) {
            const int kp  = item % 7;
            const int rem = item / 7;
            const int z   = rem % 5;
            const int col = rem / 5;
            const unsigned v = hist[z][2 * kp][col] | (hist[z][2 * kp + 1][col] << 16);
            if (v) atomicAdd(&feat_hist[((size_t)b * LVOX + col * 5 + z) * 7 + kp], v);
        }
    } else {
        const int rb    = bid - FEAT_BLOCKS;
        const int ab    = rb & 63;
        const int chunk = rb >> 6;
        const int a     = ab >> 3;
        const int b     = ab & 7;

        int* h = (int*)&hist[0][0][0];
        for (int i = tid; i < LVOX; i += 512) h[i] = 0;
        __syncthreads();

        const float C[8] = { -4.3711388e-08f, 0.3826834323650898f, 0.7071067811865476f,
                             0.9238795325112867f, 1.0f, 0.9238795325112867f,
                             0.7071067811865476f, 0.3826834323650898f };
        const float S[8] = { -1.0f, -0.9238795325112867f, -0.7071067811865476f,
                             -0.3826834323650898f, 0.0f, 0.3826834323650898f,
                             0.7071067811865476f, 0.9238795325112867f };
        const float c = C[a];
        const float s = S[a];

        const float* __restrict__ p =
            pcd + ((size_t)b * NPTS + (size_t)chunk * ROT_CHPTS) * 3;

        for (int n = tid; n < ROT_CHPTS; n += 512) {
            const float x = p[n * 3 + 0];
            const float y = p[n * 3 + 1];
            const float z = p[n * 3 + 2];
            const float rx = x * c - y * s + 5.5f;
            const float ry = x * s + y * c + 5.5f;
            const float rz = z + 2.5f;
            const int icx = (int)floorf(rx);
            const int icy = (int)floorf(ry);
            const int icz = (int)floorf(rz);
            const int flat = icz + icy * 5 + icx * 55;
            if (flat >= 0 && flat < LVOX) atomicAdd(&h[flat], 1);
        }
        __syncthreads();

        int* __restrict__ dst = rot_hist + (size_t)ab * LVOX;
        for (int i = tid; i < LVOX; i += 512) {
            const int v = h[i];
            if (v) atomicAdd(&dst[i], v);
        }
    }
}

// ---------------------------------------------------------------------------
// Finalize (unchanged).
// ---------------------------------------------------------------------------
__global__ __launch_bounds__(256) void write_kernel(const int* __restrict__ rot_hist,
                                                    const unsigned* __restrict__ feat16,
                                                    float* __restrict__ out) {
    const int gt    = blockIdx.x * 256 + threadIdx.x;
    const int group = gt >> 4;
    const int q     = gt & 15;
    if (group >= BATCH * LVOX) return;
    const int b = group / LVOX;
    const int l = group % LVOX;

    int v = 0;
    if (q < NBIN) {
        const unsigned w = feat16[(size_t)group * 7 + (q >> 1)];
        v = (int)((w >> (16 * (q & 1))) & 0xFFFFu);
    }
#pragma unroll
    for (int off = 1; off < 16; off <<= 1) {
        const int t = __shfl_up(v, off, 16);
        if (q >= off) v += t;
    }
    const float inv_n = 1.0f / (float)NPTS;
    float* __restrict__ o = out + (size_t)group * CH;
    if (q < NBIN)       o[q]  = (float)v * inv_n;
    else if (q == NBIN) o[14] = 1.0f;
    if (q < 8) {
        const int r = rot_hist[((size_t)q * BATCH + b) * LVOX + l];
        o[15 + q] = (float)r * inv_n;
    }
}

extern "C" void kernel_launch(void* const* d_in, const int* in_sizes, int n_in,
                              void* d_out, int out_size, void* d_ws, size_t ws_size,
                              hipStream_t stream) {
    const float* pcd = (const float*)d_in[0];
    float* out = (float*)d_out;
    int* rot_hist = (int*)d_ws;
    unsigned* feat16 = (unsigned*)d_ws + ROT_WS_U32;
    unsigned* sink = (unsigned*)d_ws;           // probe garbage, wiped below

    hipLaunchKernelGGL(probe_kernel<0>, dim3(FEAT_BLOCKS), dim3(512), 0, stream, pcd, sink);
    hipLaunchKernelGGL(probe_kernel<1>, dim3(FEAT_BLOCKS), dim3(512), 0, stream, pcd, sink);
    hipLaunchKernelGGL(probe_kernel<2>, dim3(FEAT_BLOCKS), dim3(512), 0, stream, pcd, sink);
    hipLaunchKernelGGL(probe_kernel<3>, dim3(FEAT_BLOCKS), dim3(512), 0, stream, pcd, sink);
    hipLaunchKernelGGL(probe_kernel<4>, dim3(FEAT_BLOCKS), dim3(512), 0, stream, pcd, sink);

    hipLaunchKernelGGL(zero_kernel, dim3((WS_U32_TOTAL + 255) / 256), dim3(256), 0,
                       stream, (unsigned*)d_ws);
    hipLaunchKernelGGL(main_kernel, dim3(FEAT_BLOCKS + ROT_BLOCKS), dim3(512), 0,
                       stream, pcd, rot_hist, feat16);
    hipLaunchKernelGGL(write_kernel, dim3((BATCH * LVOX * 16 + 255) / 256), dim3(256),
                       0, stream, rot_hist, feat16, out);
}

// Round 18
// 58.634 us; speedup vs baseline: 11.0782x; 11.0782x over previous
//
#include <hip/hip_runtime.h>

#define BATCH  8
#define NPTS   16384
#define LVOX   605     // 11*11*5 = 121 xy-columns * 5 z
#define ABINS  8
#define CH     23
#define NCOL   121
#define NBIN   14      // floor(d) <= 13 (max dist 13.89); feature[14] == 1.0
#define BPTS   256     // points per feature block
#define FEAT_BLOCKS (BATCH * (NPTS / BPTS))   // 512
#define ROT_CH    4
#define ROT_CHPTS (NPTS / ROT_CH)             // 4096
#define ROT_BLOCKS (ABINS * BATCH * ROT_CH)   // 256

#define ROT_WS_U32  (ABINS * BATCH * LVOX)          // 38720
#define FEAT_WS_U32 (BATCH * LVOX * (NBIN / 2))     // 33880 (u16 pairs)
#define WS_U32_TOTAL (ROT_WS_U32 + FEAT_WS_U32)     // 72600

// ---------------------------------------------------------------------------
// Exact floor(sqrt(d2)) WITHOUT the trans pipe (R17 ablation: wave64
// v_sqrt_f32 measures ~32-34 issue cycles; 5/point cost 17us of 22).
// Magic-estimate k~ (rel err <=3.5% => |err| <= 0.49 at d<=13.9 => k~ in
// {k-1,k,k+1}), then exact float fixup: k~^2 and (k~+1)^2 <= 196 are exactly
// representable, compares are exact.  ~11 two-cycle VALU ops, zero trans.
// ---------------------------------------------------------------------------
__device__ __forceinline__ int bin14(float d2) {
    const float st = __int_as_float((__float_as_int(d2) >> 1) + 0x1fbd1df5);
    const int   kt = (int)st;
    const float fk = (float)kt;
    const float lo = fk * fk;               // k~^2 (exact)
    const float fp = fk + 1.0f;
    const float hi = fp * fp;               // (k~+1)^2 (exact)
    return kt - 1 + (d2 >= lo ? 1 : 0) + (d2 >= hi ? 1 : 0);
}

// ---------------------------------------------------------------------------
// Workspace zeroing — own kernel, no hipMemsetAsync.
// ---------------------------------------------------------------------------
__global__ __launch_bounds__(256) void zero_kernel(unsigned* __restrict__ ws) {
    const int i = blockIdx.x * 256 + threadIdx.x;
    if (i < WS_U32_TOTAL) ws[i] = 0u;
}

// ---------------------------------------------------------------------------
// Fused kernel, 512 threads = R14 structure (best: 35.6us) with the sqrt
// replaced by bin14().  Lane = column, hist[z][k][li] conflict-free ds_add;
// points via wave-uniform s_load; packed-u16 global atomics.
// Blocks [0,512): features.  Blocks [512,768): rot histogram (unchanged).
// ---------------------------------------------------------------------------
__global__ __launch_bounds__(512) void main_kernel(const float* __restrict__ pcd,
                                                   int* __restrict__ rot_hist,
                                                   unsigned* __restrict__ feat_hist) {
    __shared__ unsigned hist[5][NBIN][128];   // 35840 B (row stride 512 B)
    const int bid = blockIdx.x;
    const int tid = threadIdx.x;

    if (bid < FEAT_BLOCKS) {
        const int b     = bid >> 6;      // /64
        const int outer = bid & 63;

        { unsigned* hp = &hist[0][0][0];
          for (int i = tid; i < 5 * NBIN * 128; i += 512) hp[i] = 0u; }

        const int li = tid & 127;                     // histogram column
        const int cc = (li < NCOL) ? li : (NCOL - 1); // clamp so k <= 13
        const float lx = -5.0f + (float)(cc / 11);
        const float ly = -5.0f + (float)(cc % 11);
        const int pbase = __builtin_amdgcn_readfirstlane(tid >> 7) * 64;
        const float* __restrict__ pp =
            pcd + ((size_t)b * NPTS + outer * BPTS + pbase) * 3;

        __syncthreads();

#pragma unroll 4
        for (int j = 0; j < 64; ++j) {
            const float px = pp[j * 3 + 0];
            const float py = pp[j * 3 + 1];
            const float pz = pp[j * 3 + 2];
            const float dx = px - lx, dy = py - ly;
            const float rxy2 = fmaf(dy, dy, dx * dx);
            const float dz0 = pz + 2.0f;
#pragma unroll
            for (int z = 0; z < 5; ++z) {
                const float dz = dz0 - (float)z;
                const int k = bin14(fmaf(dz, dz, rxy2));
                atomicAdd(&hist[z][k][li], 1u);       // ds_add, conflict-free
            }
        }
        __syncthreads();

        // ---- epilogue: pack bin pairs (u16|u16), one global atomic each ----
        for (int item = tid; item < NCOL * 5 * (NBIN / 2); item += 512) {
            const int kp  = item % 7;
            const int rem = item / 7;
            const int z   = rem % 5;
            const int col = rem / 5;
            const unsigned v = hist[z][2 * kp][col] | (hist[z][2 * kp + 1][col] << 16);
            if (v) atomicAdd(&feat_hist[((size_t)b * LVOX + col * 5 + z) * 7 + kp], v);
        }
    } else {
        // ------------------ rotation-voxel histogram ------------------
        const int rb    = bid - FEAT_BLOCKS;
        const int ab    = rb & 63;        // a*8 + b
        const int chunk = rb >> 6;        // 0..3
        const int a     = ab >> 3;
        const int b     = ab & 7;

        int* h = (int*)&hist[0][0][0];
        for (int i = tid; i < LVOX; i += 512) h[i] = 0;
        __syncthreads();

        const float C[8] = { -4.3711388e-08f, 0.3826834323650898f, 0.7071067811865476f,
                             0.9238795325112867f, 1.0f, 0.9238795325112867f,
                             0.7071067811865476f, 0.3826834323650898f };
        const float S[8] = { -1.0f, -0.9238795325112867f, -0.7071067811865476f,
                             -0.3826834323650898f, 0.0f, 0.3826834323650898f,
                             0.7071067811865476f, 0.9238795325112867f };
        const float c = C[a];
        const float s = S[a];

        const float* __restrict__ p =
            pcd + ((size_t)b * NPTS + (size_t)chunk * ROT_CHPTS) * 3;

        for (int n = tid; n < ROT_CHPTS; n += 512) {
            const float x = p[n * 3 + 0];
            const float y = p[n * 3 + 1];
            const float z = p[n * 3 + 2];
            const float rx = x * c - y * s + 5.5f;
            const float ry = x * s + y * c + 5.5f;
            const float rz = z + 2.5f;
            const int icx = (int)floorf(rx);
            const int icy = (int)floorf(ry);
            const int icz = (int)floorf(rz);
            const int flat = icz + icy * 5 + icx * 55;
            if (flat >= 0 && flat < LVOX) atomicAdd(&h[flat], 1);
        }
        __syncthreads();

        int* __restrict__ dst = rot_hist + (size_t)ab * LVOX;
        for (int i = tid; i < LVOX; i += 512) {
            const int v = h[i];
            if (v) atomicAdd(&dst[i], v);
        }
    }
}

// ---------------------------------------------------------------------------
// Finalize.  16-lane groups per (b,l): lane q<14 loads its u16 bin count,
// inclusive prefix-scan -> cumulative feature; feature[14] == 1.0 exactly.
// Lanes 0..7 also write the 8 rot channels.
// ---------------------------------------------------------------------------
__global__ __launch_bounds__(256) void write_kernel(const int* __restrict__ rot_hist,
                                                    const unsigned* __restrict__ feat16,
                                                    float* __restrict__ out) {
    const int gt    = blockIdx.x * 256 + threadIdx.x;
    const int group = gt >> 4;                 // (b,l)
    const int q     = gt & 15;
    if (group >= BATCH * LVOX) return;
    const int b = group / LVOX;
    const int l = group % LVOX;

    int v = 0;
    if (q < NBIN) {
        const unsigned w = feat16[(size_t)group * 7 + (q >> 1)];
        v = (int)((w >> (16 * (q & 1))) & 0xFFFFu);
    }
#pragma unroll
    for (int off = 1; off < 16; off <<= 1) {
        const int t = __shfl_up(v, off, 16);
        if (q >= off) v += t;
    }
    const float inv_n = 1.0f / (float)NPTS;
    float* __restrict__ o = out + (size_t)group * CH;
    if (q < NBIN)       o[q]  = (float)v * inv_n;
    else if (q == NBIN) o[14] = 1.0f;
    if (q < 8) {
        const int r = rot_hist[((size_t)q * BATCH + b) * LVOX + l];
        o[15 + q] = (float)r * inv_n;
    }
}

extern "C" void kernel_launch(void* const* d_in, const int* in_sizes, int n_in,
                              void* d_out, int out_size, void* d_ws, size_t ws_size,
                              hipStream_t stream) {
    const float* pcd = (const float*)d_in[0];
    float* out = (float*)d_out;
    int* rot_hist = (int*)d_ws;
    unsigned* feat16 = (unsigned*)d_ws + ROT_WS_U32;

    hipLaunchKernelGGL(zero_kernel, dim3((WS_U32_TOTAL + 255) / 256), dim3(256), 0,
                       stream, (unsigned*)d_ws);
    hipLaunchKernelGGL(main_kernel, dim3(FEAT_BLOCKS + ROT_BLOCKS), dim3(512), 0,
                       stream, pcd, rot_hist, feat16);
    hipLaunchKernelGGL(write_kernel, dim3((BATCH * LVOX * 16 + 255) / 256), dim3(256),
                       0, stream, rot_hist, feat16, out);
}

// Round 19
// 42.366 us; speedup vs baseline: 15.3323x; 1.3840x over previous
//
#include <hip/hip_runtime.h>

#define BATCH  8
#define NPTS   16384
#define LVOX   605     // 11*11*5 = 121 xy-columns * 5 z
#define ABINS  8
#define CH     23
#define NCOL   121
#define NBIN   14      // floor(d) <= 13 (max dist 13.89); feature[14] == 1.0
#define BPTS   256     // points per feature block
#define FEAT_BLOCKS (BATCH * (NPTS / BPTS))   // 512
#define ROT_CH    4
#define ROT_CHPTS (NPTS / ROT_CH)             // 4096
#define ROT_BLOCKS (ABINS * BATCH * ROT_CH)   // 256

#define ROT_WS_U32  (ABINS * BATCH * LVOX)          // 38720
#define FEAT_WS_U32 (BATCH * LVOX * (NBIN / 2))     // 33880 (u16 pairs)
#define WS_U32_TOTAL (ROT_WS_U32 + FEAT_WS_U32)     // 72600

// ---------------------------------------------------------------------------
// floor(sqrt(d2)) via BIASED magic + single sign fixup.  R17/R18 calibration:
// wave64 v_sqrt_f32 ~30 issue cycles (dominated R14); R18's compare-ladder
// fixup compiled to ~25-30 ops (cndmask/VCC bloat).  This version: magic
// constant 0x1FBD1DF5 pre-biased by x1.028 (+0x5196C) so est >= d always
// (base err in [-2.2%,+4.5%], biased err in [+0.5%,+7.6%]) and est < 15 for
// d <= 13.89 => kt=(int)est in {k,k+1} (kt=14 only when k=13; lo=196 > d2max
// auto-fixes).  Fixup: k = kt + sign_bit(d2 - kt^2) (0 or -1) — no VCC, no
// trans, ~12 lean VALU ops.  min(k,13) = 1-op table-overrun insurance.
// ---------------------------------------------------------------------------
__device__ __forceinline__ int bin_magic(float d2) {
    const float est = __int_as_float((__float_as_int(d2) >> 1) + 0x1FC23761);
    const int   kt  = (int)est;
    const float fk  = (float)kt;
    const float t   = d2 - fk * fk;              // exact: fk^2 <= 196 exact
    const int   k   = kt + (__float_as_int(t) >> 31);
    return (k < 13) ? k : 13;
}

// ---------------------------------------------------------------------------
// Workspace zeroing — own kernel, no hipMemsetAsync.
// ---------------------------------------------------------------------------
__global__ __launch_bounds__(256) void zero_kernel(unsigned* __restrict__ ws) {
    const int i = blockIdx.x * 256 + threadIdx.x;
    if (i < WS_U32_TOTAL) ws[i] = 0u;
}

// ---------------------------------------------------------------------------
// Fused kernel, 512 threads = R14 structure (best: 35.6us) with sqrt
// replaced by bin_magic().  Lane = column, hist[z][k][li] conflict-free
// ds_add; points via wave-uniform s_load; packed-u16 global atomics.
// Blocks [0,512): features.  Blocks [512,768): rot histogram (unchanged).
// ---------------------------------------------------------------------------
__global__ __launch_bounds__(512) void main_kernel(const float* __restrict__ pcd,
                                                   int* __restrict__ rot_hist,
                                                   unsigned* __restrict__ feat_hist) {
    __shared__ unsigned hist[5][NBIN][128];   // 35840 B (row stride 512 B)
    const int bid = blockIdx.x;
    const int tid = threadIdx.x;

    if (bid < FEAT_BLOCKS) {
        const int b     = bid >> 6;      // /64
        const int outer = bid & 63;

        { unsigned* hp = &hist[0][0][0];
          for (int i = tid; i < 5 * NBIN * 128; i += 512) hp[i] = 0u; }

        const int li = tid & 127;                     // histogram column
        const int cc = (li < NCOL) ? li : (NCOL - 1); // clamp so k <= 13
        const float lx = -5.0f + (float)(cc / 11);
        const float ly = -5.0f + (float)(cc % 11);
        const int pbase = __builtin_amdgcn_readfirstlane(tid >> 7) * 64;
        const float* __restrict__ pp =
            pcd + ((size_t)b * NPTS + outer * BPTS + pbase) * 3;

        __syncthreads();

#pragma unroll 4
        for (int j = 0; j < 64; ++j) {
            const float px = pp[j * 3 + 0];
            const float py = pp[j * 3 + 1];
            const float pz = pp[j * 3 + 2];
            const float dx = px - lx, dy = py - ly;
            const float rxy2 = fmaf(dy, dy, dx * dx);
            const float dz0 = pz + 2.0f;
#pragma unroll
            for (int z = 0; z < 5; ++z) {
                const float dz = dz0 - (float)z;
                const int k = bin_magic(fmaf(dz, dz, rxy2));
                atomicAdd(&hist[z][k][li], 1u);       // ds_add, conflict-free
            }
        }
        __syncthreads();

        // ---- epilogue: pack bin pairs (u16|u16), one global atomic each ----
        for (int item = tid; item < NCOL * 5 * (NBIN / 2); item += 512) {
            const int kp  = item % 7;
            const int rem = item / 7;
            const int z   = rem % 5;
            const int col = rem / 5;
            const unsigned v = hist[z][2 * kp][col] | (hist[z][2 * kp + 1][col] << 16);
            if (v) atomicAdd(&feat_hist[((size_t)b * LVOX + col * 5 + z) * 7 + kp], v);
        }
    } else {
        // ------------------ rotation-voxel histogram ------------------
        const int rb    = bid - FEAT_BLOCKS;
        const int ab    = rb & 63;        // a*8 + b
        const int chunk = rb >> 6;        // 0..3
        const int a     = ab >> 3;
        const int b     = ab & 7;

        int* h = (int*)&hist[0][0][0];
        for (int i = tid; i < LVOX; i += 512) h[i] = 0;
        __syncthreads();

        const float C[8] = { -4.3711388e-08f, 0.3826834323650898f, 0.7071067811865476f,
                             0.9238795325112867f, 1.0f, 0.9238795325112867f,
                             0.7071067811865476f, 0.3826834323650898f };
        const float S[8] = { -1.0f, -0.9238795325112867f, -0.7071067811865476f,
                             -0.3826834323650898f, 0.0f, 0.3826834323650898f,
                             0.7071067811865476f, 0.9238795325112867f };
        const float c = C[a];
        const float s = S[a];

        const float* __restrict__ p =
            pcd + ((size_t)b * NPTS + (size_t)chunk * ROT_CHPTS) * 3;

        for (int n = tid; n < ROT_CHPTS; n += 512) {
            const float x = p[n * 3 + 0];
            const float y = p[n * 3 + 1];
            const float z = p[n * 3 + 2];
            const float rx = x * c - y * s + 5.5f;
            const float ry = x * s + y * c + 5.5f;
            const float rz = z + 2.5f;
            const int icx = (int)floorf(rx);
            const int icy = (int)floorf(ry);
            const int icz = (int)floorf(rz);
            const int flat = icz + icy * 5 + icx * 55;
            if (flat >= 0 && flat < LVOX) atomicAdd(&h[flat], 1);
        }
        __syncthreads();

        int* __restrict__ dst = rot_hist + (size_t)ab * LVOX;
        for (int i = tid; i < LVOX; i += 512) {
            const int v = h[i];
            if (v) atomicAdd(&dst[i], v);
        }
    }
}

// ---------------------------------------------------------------------------
// Finalize.  16-lane groups per (b,l): lane q<14 loads its u16 bin count,
// inclusive prefix-scan -> cumulative feature; feature[14] == 1.0 exactly.
// Lanes 0..7 also write the 8 rot channels.
// ---------------------------------------------------------------------------
__global__ __launch_bounds__(256) void write_kernel(const int* __restrict__ rot_hist,
                                                    const unsigned* __restrict__ feat16,
                                                    float* __restrict__ out) {
    const int gt    = blockIdx.x * 256 + threadIdx.x;
    const int group = gt >> 4;                 // (b,l)
    const int q     = gt & 15;
    if (group >= BATCH * LVOX) return;
    const int b = group / LVOX;
    const int l = group % LVOX;

    int v = 0;
    if (q < NBIN) {
        const unsigned w = feat16[(size_t)group * 7 + (q >> 1)];
        v = (int)((w >> (16 * (q & 1))) & 0xFFFFu);
    }
#pragma unroll
    for (int off = 1; off < 16; off <<= 1) {
        const int t = __shfl_up(v, off, 16);
        if (q >= off) v += t;
    }
    const float inv_n = 1.0f / (float)NPTS;
    float* __restrict__ o = out + (size_t)group * CH;
    if (q < NBIN)       o[q]  = (float)v * inv_n;
    else if (q == NBIN) o[14] = 1.0f;
    if (q < 8) {
        const int r = rot_hist[((size_t)q * BATCH + b) * LVOX + l];
        o[15 + q] = (float)r * inv_n;
    }
}

extern "C" void kernel_launch(void* const* d_in, const int* in_sizes, int n_in,
                              void* d_out, int out_size, void* d_ws, size_t ws_size,
                              hipStream_t stream) {
    const float* pcd = (const float*)d_in[0];
    float* out = (float*)d_out;
    int* rot_hist = (int*)d_ws;
    unsigned* feat16 = (unsigned*)d_ws + ROT_WS_U32;

    hipLaunchKernelGGL(zero_kernel, dim3((WS_U32_TOTAL + 255) / 256), dim3(256), 0,
                       stream, (unsigned*)d_ws);
    hipLaunchKernelGGL(main_kernel, dim3(FEAT_BLOCKS + ROT_BLOCKS), dim3(512), 0,
                       stream, pcd, rot_hist, feat16);
    hipLaunchKernelGGL(write_kernel, dim3((BATCH * LVOX * 16 + 255) / 256), dim3(256),
                       0, stream, rot_hist, feat16, out);
}

// Round 20
// 42.199 us; speedup vs baseline: 15.3930x; 1.0040x over previous
//
#include <hip/hip_runtime.h>

#define BATCH  8
#define NPTS   16384
#define LVOX   605     // 11*11*5 = 121 xy-columns * 5 z
#define ABINS  8
#define CH     23
#define NCOL   121
#define NBIN   14      // floor(d) <= 13 (max dist 13.89); feature[14] == 1.0
#define SPTS   32      // points per 128-lane group (R20: halved -> 2x blocks)
#define BPTS   (SPTS * 4)                     // 128 points per feature block
#define FEAT_BLOCKS (BATCH * (NPTS / BPTS))   // 8*128 = 1024
#define ROT_CH    4
#define ROT_CHPTS (NPTS / ROT_CH)             // 4096
#define ROT_BLOCKS (ABINS * BATCH * ROT_CH)   // 256

#define ROT_WS_U32  (ABINS * BATCH * LVOX)          // 38720
#define FEAT_WS_U32 (BATCH * LVOX * (NBIN / 2))     // 33880 (u16 pairs)
#define WS_U32_TOTAL (ROT_WS_U32 + FEAT_WS_U32)     // 72600

// ---------------------------------------------------------------------------
// Workspace zeroing — own kernel, no hipMemsetAsync.
// ---------------------------------------------------------------------------
__global__ __launch_bounds__(256) void zero_kernel(unsigned* __restrict__ ws) {
    const int i = blockIdx.x * 256 + threadIdx.x;
    if (i < WS_U32_TOTAL) ws[i] = 0u;
}

// ---------------------------------------------------------------------------
// Fused kernel, 512 threads = R14 structure (proven best, 35.6us) with
// DOUBLED BLOCK COUNT (SPTS 64->32).  R18/R19 post-mortem: real kernel is
// point-load-latency-bound (probes with hot caches hit 91% VALUBusy; real
// kernel ~40%), so offer more independent waves: 1280 blocks = 5/CU offered,
// 4/CU resident (LDS 35.8KB caps at 4 = 32 waves = full occupancy).
// Binning stays v_sqrt (R18/R19 proved lean-op alternatives regress when
// latency-bound).  Lane = column, hist[z][k][li] conflict-free ds_add;
// points via wave-uniform s_load; packed-u16 global atomics.
// Blocks [0,1024): features.  Blocks [1024,1280): rot histogram.
// ---------------------------------------------------------------------------
__global__ __launch_bounds__(512) void main_kernel(const float* __restrict__ pcd,
                                                   int* __restrict__ rot_hist,
                                                   unsigned* __restrict__ feat_hist) {
    __shared__ unsigned hist[5][NBIN][128];   // 35840 B (row stride 512 B)
    const int bid = blockIdx.x;
    const int tid = threadIdx.x;

    if (bid < FEAT_BLOCKS) {
        const int b     = bid >> 7;      // /128
        const int outer = bid & 127;

        { unsigned* hp = &hist[0][0][0];
          for (int i = tid; i < 5 * NBIN * 128; i += 512) hp[i] = 0u; }

        const int li = tid & 127;                     // histogram column
        const int cc = (li < NCOL) ? li : (NCOL - 1); // clamp so k <= 13
        const float lx = -5.0f + (float)(cc / 11);
        const float ly = -5.0f + (float)(cc % 11);
        const int pbase = __builtin_amdgcn_readfirstlane(tid >> 7) * SPTS;
        const float* __restrict__ pp =
            pcd + ((size_t)b * NPTS + outer * BPTS + pbase) * 3;

        __syncthreads();

#pragma unroll 4
        for (int j = 0; j < SPTS; ++j) {
            const float px = pp[j * 3 + 0];
            const float py = pp[j * 3 + 1];
            const float pz = pp[j * 3 + 2];
            const float dx = px - lx, dy = py - ly;
            const float rxy2 = fmaf(dy, dy, dx * dx);
            const float dz0 = pz + 2.0f;
#pragma unroll
            for (int z = 0; z < 5; ++z) {
                const float dz = dz0 - (float)z;
                const float d  = __builtin_amdgcn_sqrtf(fmaf(dz, dz, rxy2));
                atomicAdd(&hist[z][(int)d][li], 1u);  // ds_add, conflict-free
            }
        }
        __syncthreads();

        // ---- epilogue: pack bin pairs (u16|u16), one global atomic each ----
        for (int item = tid; item < NCOL * 5 * (NBIN / 2); item += 512) {
            const int kp  = item % 7;
            const int rem = item / 7;
            const int z   = rem % 5;
            const int col = rem / 5;
            const unsigned v = hist[z][2 * kp][col] | (hist[z][2 * kp + 1][col] << 16);
            if (v) atomicAdd(&feat_hist[((size_t)b * LVOX + col * 5 + z) * 7 + kp], v);
        }
    } else {
        // ------------------ rotation-voxel histogram ------------------
        const int rb    = bid - FEAT_BLOCKS;
        const int ab    = rb & 63;        // a*8 + b
        const int chunk = rb >> 6;        // 0..3
        const int a     = ab >> 3;
        const int b     = ab & 7;

        int* h = (int*)&hist[0][0][0];
        for (int i = tid; i < LVOX; i += 512) h[i] = 0;
        __syncthreads();

        const float C[8] = { -4.3711388e-08f, 0.3826834323650898f, 0.7071067811865476f,
                             0.9238795325112867f, 1.0f, 0.9238795325112867f,
                             0.7071067811865476f, 0.3826834323650898f };
        const float S[8] = { -1.0f, -0.9238795325112867f, -0.7071067811865476f,
                             -0.3826834323650898f, 0.0f, 0.3826834323650898f,
                             0.7071067811865476f, 0.9238795325112867f };
        const float c = C[a];
        const float s = S[a];

        const float* __restrict__ p =
            pcd + ((size_t)b * NPTS + (size_t)chunk * ROT_CHPTS) * 3;

        for (int n = tid; n < ROT_CHPTS; n += 512) {
            const float x = p[n * 3 + 0];
            const float y = p[n * 3 + 1];
            const float z = p[n * 3 + 2];
            const float rx = x * c - y * s + 5.5f;
            const float ry = x * s + y * c + 5.5f;
            const float rz = z + 2.5f;
            const int icx = (int)floorf(rx);
            const int icy = (int)floorf(ry);
            const int icz = (int)floorf(rz);
            const int flat = icz + icy * 5 + icx * 55;
            if (flat >= 0 && flat < LVOX) atomicAdd(&h[flat], 1);
        }
        __syncthreads();

        int* __restrict__ dst = rot_hist + (size_t)ab * LVOX;
        for (int i = tid; i < LVOX; i += 512) {
            const int v = h[i];
            if (v) atomicAdd(&dst[i], v);
        }
    }
}

// ---------------------------------------------------------------------------
// Finalize.  16-lane groups per (b,l): lane q<14 loads its u16 bin count,
// inclusive prefix-scan -> cumulative feature; feature[14] == 1.0 exactly.
// Lanes 0..7 also write the 8 rot channels.
// ---------------------------------------------------------------------------
__global__ __launch_bounds__(256) void write_kernel(const int* __restrict__ rot_hist,
                                                    const unsigned* __restrict__ feat16,
                                                    float* __restrict__ out) {
    const int gt    = blockIdx.x * 256 + threadIdx.x;
    const int group = gt >> 4;                 // (b,l)
    const int q     = gt & 15;
    if (group >= BATCH * LVOX) return;
    const int b = group / LVOX;
    const int l = group % LVOX;

    int v = 0;
    if (q < NBIN) {
        const unsigned w = feat16[(size_t)group * 7 + (q >> 1)];
        v = (int)((w >> (16 * (q & 1))) & 0xFFFFu);
    }
#pragma unroll
    for (int off = 1; off < 16; off <<= 1) {
        const int t = __shfl_up(v, off, 16);
        if (q >= off) v += t;
    }
    const float inv_n = 1.0f / (float)NPTS;
    float* __restrict__ o = out + (size_t)group * CH;
    if (q < NBIN)       o[q]  = (float)v * inv_n;
    else if (q == NBIN) o[14] = 1.0f;
    if (q < 8) {
        const int r = rot_hist[((size_t)q * BATCH + b) * LVOX + l];
        o[15 + q] = (float)r * inv_n;
    }
}

extern "C" void kernel_launch(void* const* d_in, const int* in_sizes, int n_in,
                              void* d_out, int out_size, void* d_ws, size_t ws_size,
                              hipStream_t stream) {
    const float* pcd = (const float*)d_in[0];
    float* out = (float*)d_out;
    int* rot_hist = (int*)d_ws;
    unsigned* feat16 = (unsigned*)d_ws + ROT_WS_U32;

    hipLaunchKernelGGL(zero_kernel, dim3((WS_U32_TOTAL + 255) / 256), dim3(256), 0,
                       stream, (unsigned*)d_ws);
    hipLaunchKernelGGL(main_kernel, dim3(FEAT_BLOCKS + ROT_BLOCKS), dim3(512), 0,
                       stream, pcd, rot_hist, feat16);
    hipLaunchKernelGGL(write_kernel, dim3((BATCH * LVOX * 16 + 255) / 256), dim3(256),
                       0, stream, rot_hist, feat16, out);
}